// Round 1
// baseline (6240.819 us; speedup 1.0000x reference)
//
#include <hip/hip_runtime.h>

// CustomRNN: S=2048 steps, B=64, I=256, H=512, E=256.
//   m_t = h_{t-1} @ We.T + be ;  h_t = tanh([x_t, m_{t-1}] @ Wih.T + bih)
// Rewrite: h_t = tanh(x_t@Wx.T + bih + be@Wm.T + h_{t-2}@W2),  W2 = We.T@Wm.T
//  -> two independent parity chains, 1024 sequential supersteps.
//
// This version removes the fence-based exchange entirely:
//  * x@Wx.T precomputed by k_xw (MFMA GEMM) directly INTO the out buffer;
//    each lane reads its xw value one superstep before overwriting it with h.
//  * hx exchange through MALL (Infinity Cache) with sc0 sc1 bypass ops:
//    producer: sc0sc1 stores -> vmcnt(0) -> sc0sc1 per-wave flag store.
//    consumer: poll 32 flags (system-scope relaxed loads) -> load fragments
//    directly into registers with system-scope relaxed loads.
//    No buffer_wbl2 / buffer_inv / atomic RMW; zero __syncthreads in k_main.

#define S2    1024
#define OUT_HT 67108864          // 2048*64*512
#define OUT_MT 67141632          // + 64*512

typedef _Float16 half8 __attribute__((ext_vector_type(8)));
typedef float f32x4 __attribute__((ext_vector_type(4)));
typedef unsigned long long u64x2 __attribute__((ext_vector_type(2)));

// ---- workspace layout (bytes) ----
#define OFF_W2F   0u         // 512*512 f16 fragment-ordered  (524288)
#define OFF_WXF   524288u    // 512*256 f16 fragment-ordered  (262144)
#define OFF_C2    786432u    // 512 f32   bih + be@Wm.T
#define OFF_AVE   788480u    // 64*512 f32  bih + m0@Wm.T          (t=0 addvec)
#define OFF_AVO   919552u    // 64*512 f32  bih + (h0@We.T+be)@Wm.T (t=1 addvec)
#define OFF_MEMB  1050624u   // 64*256 f32  h0@We.T+be
#define OFF_HX    1116160u   // 2*8*16*512 f16 exchange (262144)
#define OFF_FLG   1378304u   // 256 u32 per-wave flags

// ---------------- prep 1: memb = h0@We.T + be ----------------
__global__ __launch_bounds__(256) void k_memb(const float* __restrict__ h0,
                                              const float* __restrict__ We,
                                              const float* __restrict__ be,
                                              float* __restrict__ memb) {
  __shared__ float hs[512];
  int b = blockIdx.x, e = threadIdx.x;
  for (int i = threadIdx.x; i < 512; i += 256) hs[i] = h0[b * 512 + i];
  __syncthreads();
  float acc = be[e];
  const float* wr = We + (size_t)e * 512;
  for (int h = 0; h < 512; ++h) acc += hs[h] * wr[h];
  memb[b * 256 + e] = acc;
}

// ---------------- prep 2: weights->fragments, addvecs, flags ----------------
__global__ __launch_bounds__(256) void k_prep(
    const float* __restrict__ We, const float* __restrict__ be,
    const float* __restrict__ Wih, const float* __restrict__ bih,
    const float* __restrict__ m0, const float* __restrict__ memb,
    _Float16* __restrict__ w2f, _Float16* __restrict__ wxf,
    float* __restrict__ c2, float* __restrict__ ave, float* __restrict__ avo,
    unsigned int* __restrict__ flg) {
  int blk = blockIdx.x, tid = threadIdx.x;
  if (blk < 1024) {                       // W2[k][n] = sum_e We[e,k]*Wih[n,256+e]
    int idx = blk * 256 + tid;
    int k = idx & 511, n = idx >> 9;
    float acc = 0.f;
    for (int e = 0; e < 256; ++e)
      acc += We[e * 512 + k] * Wih[n * 512 + 256 + e];
    int ntile = n >> 4, nl = n & 15;
    int kch = k >> 5, kq = (k >> 3) & 3, ke = k & 7;
    int lane = kq * 16 + nl;
    w2f[(size_t)((ntile * 16 + kch) * 64 + lane) * 8 + ke] = (_Float16)acc;
  } else if (blk < 1536) {                // Wx[k][n] = Wih[n][k], k<256
    int idx = (blk - 1024) * 256 + tid;
    int k = idx & 255, n = idx >> 8;
    float v = Wih[n * 512 + k];
    int ntile = n >> 4, nl = n & 15;
    int kch = k >> 5, kq = (k >> 3) & 3, ke = k & 7;
    int lane = kq * 16 + nl;
    wxf[(size_t)((ntile * 8 + kch) * 64 + lane) * 8 + ke] = (_Float16)v;
  } else if (blk < 1538) {                // c2 = bih + be@Wm.T
    int j = (blk - 1536) * 256 + tid;
    float acc = bih[j];
    for (int e = 0; e < 256; ++e) acc += be[e] * Wih[j * 512 + 256 + e];
    c2[j] = acc;
  } else if (blk < 1666) {                // ave = bih + m0@Wm.T
    int i = blk - 1538;
    int b = i >> 1, j = (i & 1) * 256 + tid;
    float acc = bih[j];
    for (int e = 0; e < 256; ++e) acc += m0[b * 256 + e] * Wih[j * 512 + 256 + e];
    ave[b * 512 + j] = acc;
  } else if (blk < 1794) {                // avo = bih + memb@Wm.T
    int i = blk - 1666;
    int b = i >> 1, j = (i & 1) * 256 + tid;
    float acc = bih[j];
    for (int e = 0; e < 256; ++e) acc += memb[b * 256 + e] * Wih[j * 512 + 256 + e];
    avo[b * 512 + j] = acc;
  } else {
    flg[tid] = 0u;                        // 256 per-wave flags
  }
}

// ---------------- precompute xw = x @ Wx.T into out buffer ----------------
// rows = t*64+b (131072), cols = 512. Each out location holds xw until the
// owning k_main lane consumes it and overwrites it with h.
__global__ __launch_bounds__(512, 1) void k_xw(const float* __restrict__ x,
                                               const _Float16* __restrict__ wxf,
                                               float* __restrict__ out) {
  __shared__ _Float16 ha[128 * 264];      // 128 rows x 256 K, +8 pad (2-way free)
  const int tid = threadIdx.x;
  const int rowbase = blockIdx.x * 128;
  {                                       // stage x rows -> f16 LDS
    int r0 = tid >> 2, cs = (tid & 3) * 64;
    const float* xp = x + (size_t)(rowbase + r0) * 256 + cs;
    _Float16* dp = ha + r0 * 264 + cs;
#pragma unroll
    for (int i = 0; i < 16; ++i) {
      float4 v = *(const float4*)(xp + i * 4);
      dp[i * 4 + 0] = (_Float16)v.x; dp[i * 4 + 1] = (_Float16)v.y;
      dp[i * 4 + 2] = (_Float16)v.z; dp[i * 4 + 3] = (_Float16)v.w;
    }
  }
  __syncthreads();
  const int wv = tid >> 6, lane = tid & 63;
  const int q = lane >> 4, nl = lane & 15;
  half8 bfr[4][8];                        // wave wv owns cols [wv*64, wv*64+64)
#pragma unroll
  for (int nt = 0; nt < 4; ++nt)
#pragma unroll
    for (int kc = 0; kc < 8; ++kc)
      bfr[nt][kc] = *(const half8*)(wxf + (size_t)((((4 * wv + nt) * 8 + kc) * 64 + lane)) * 8);
  for (int ch = 0; ch < 8; ++ch) {
    f32x4 acc[4] = {{0.f,0.f,0.f,0.f},{0.f,0.f,0.f,0.f},{0.f,0.f,0.f,0.f},{0.f,0.f,0.f,0.f}};
#pragma unroll
    for (int kc = 0; kc < 8; ++kc) {
      half8 a = *(const half8*)(ha + (ch * 16 + nl) * 264 + kc * 32 + q * 8);
#pragma unroll
      for (int nt = 0; nt < 4; ++nt)
        acc[nt] = __builtin_amdgcn_mfma_f32_16x16x32_f16(a, bfr[nt][kc], acc[nt], 0, 0, 0);
    }
    int row = rowbase + ch * 16 + q * 4;
#pragma unroll
    for (int nt = 0; nt < 4; ++nt)
#pragma unroll
      for (int r = 0; r < 4; ++r)
        out[(size_t)(row + r) * 512 + wv * 64 + nt * 16 + nl] = acc[nt][r];
  }
}

__device__ inline float fast_tanh(float x) {
  float z = __expf(2.f * x);
  return 1.f - 2.f / (z + 1.f);          // saturates correctly at +-1
}

// ---------------- main sequential kernel ----------------
// Zero LDS, zero barriers; 4 independent waves per WG, each owning 16 cols.
__global__ __launch_bounds__(256, 1) void k_main(
    const _Float16* __restrict__ w2f, const float* __restrict__ c2,
    const float* __restrict__ ave, const float* __restrict__ avo,
    _Float16* __restrict__ hx, unsigned int* __restrict__ flags,
    float* __restrict__ out) {
  const int tid = threadIdx.x;
  const int g = blockIdx.x & 7;          // group: 8 batch rows x 2 parities
  const int w = blockIdx.x >> 3;         // member 0..7, owns cols [w*64, +64)
  const int wave = tid >> 6, lane = tid & 63;
  const int q = lane >> 4, nl = lane & 15;
  const int ntile = w * 4 + wave;
  const int j = (ntile << 4) + nl;       // global output column

  half8 w2r[16];
#pragma unroll
  for (int kc = 0; kc < 16; ++kc)
    w2r[kc] = *(const half8*)(w2f + (size_t)((ntile * 16 + kc) * 64 + lane) * 8);

  const float c2l = c2[j];
  float av0[4];
#pragma unroll
  for (int r = 0; r < 4; ++r) {
    int m = q * 4 + r;
    av0[r] = (m < 8) ? ave[(g * 8 + m) * 512 + j] : avo[(g * 8 + (m & 7)) * 512 + j];
  }

  const unsigned int* fp = flags + g * 32;           // group's 32 wave-flags
  unsigned int* myflag = flags + g * 32 + w * 4 + wave;

  // hx index ((p*8+g)*16 + m)*512 + col  ==  p*65536 + (g*16+m)*512 + col
  const _Float16* hxl = hx + (size_t)(g * 16 + nl) * 512 + q * 8;   // + p*65536 + kc*32
  _Float16* hxs = hx + (size_t)(g * 16 + q * 4) * 512 + j;          // + p*65536 + r*512

  float* outp[4];
#pragma unroll
  for (int r = 0; r < 4; ++r) {
    int m = q * 4 + r;
    outp[r] = out + (size_t)((m >> 3) * 64 + g * 8 + (m & 7)) * 512 + j;
  }
  float xwc[4];                           // xw prefetch (written by k_xw)
#pragma unroll
  for (int r = 0; r < 4; ++r) xwc[r] = *outp[r];

  for (int s = 0; s < S2; ++s) {
    f32x4 acc[4] = {{0.f,0.f,0.f,0.f},{0.f,0.f,0.f,0.f},{0.f,0.f,0.f,0.f},{0.f,0.f,0.f,0.f}};
    if (s > 0) {
      // wait: all 32 producer waves of this group published superstep s-1
      if (lane < 32) {
        const unsigned int* f1 = fp + lane;
        const unsigned int tgt = (unsigned int)s;
        while (__hip_atomic_load(f1, __ATOMIC_RELAXED, __HIP_MEMORY_SCOPE_SYSTEM) < tgt) {}
      }
      __builtin_amdgcn_sched_barrier(0);
      // load h_prev fragments straight into registers, bypassing L1/L2
      const _Float16* hb = hxl + (((s - 1) & 1) ? 65536 : 0);
      half8 hr[16];
#pragma unroll
      for (int kc = 0; kc < 16; ++kc) {
        const unsigned long long* p = (const unsigned long long*)(hb + kc * 32);
        u64x2 t;
        t.x = __hip_atomic_load(p,     __ATOMIC_RELAXED, __HIP_MEMORY_SCOPE_SYSTEM);
        t.y = __hip_atomic_load(p + 1, __ATOMIC_RELAXED, __HIP_MEMORY_SCOPE_SYSTEM);
        hr[kc] = __builtin_bit_cast(half8, t);
      }
#pragma unroll
      for (int kc = 0; kc < 16; ++kc)
        acc[kc & 3] = __builtin_amdgcn_mfma_f32_16x16x32_f16(hr[kc], w2r[kc], acc[kc & 3], 0, 0, 0);
    }

    // epilogue: bias + xw + tanh, write out + exchange slice (bypass stores)
    _Float16* hsp = hxs + ((s & 1) ? 65536 : 0);
#pragma unroll
    for (int r = 0; r < 4; ++r) {
      float pre = acc[0][r] + acc[1][r] + acc[2][r] + acc[3][r] + xwc[r] +
                  (s == 0 ? av0[r] : c2l);
      float h = fast_tanh(pre);
      *outp[r] = h;                                      // overwrites consumed xw
      if (s == S2 - 1 && q >= 2)                         // h_T (odd parity, t=2047)
        out[(size_t)OUT_HT + (g * 8 + ((q - 2) * 4 + r)) * 512 + j] = h;
      unsigned int hv = (unsigned int)__builtin_bit_cast(unsigned short, (_Float16)h);
      asm volatile("global_store_short %0, %1, off sc0 sc1"
                   :: "v"(hsp + r * 512), "v"(hv) : "memory");
    }
    // publish: drain stores to the coherent point, then flag (no fences)
    asm volatile("s_waitcnt vmcnt(0)" ::: "memory");
    if (lane == 0) {
      unsigned int sv = (unsigned int)(s + 1);
      asm volatile("global_store_dword %0, %1, off sc0 sc1"
                   :: "v"(myflag), "v"(sv) : "memory");
    }
    // prefetch next superstep's xw (issued after the flag, so the next
    // vmcnt(0) never waits on a fresh HBM access)
#pragma unroll
    for (int r = 0; r < 4; ++r) {
      outp[r] += 65536;                   // 2*64*512 floats per superstep
      if (s + 1 < S2) xwc[r] = *outp[r];
    }
  }
}

// ---------------- final m_T = h_2046 @ We.T + be ----------------
__global__ __launch_bounds__(256) void k_mt(float* __restrict__ out,
                                            const float* __restrict__ We,
                                            const float* __restrict__ be) {
  __shared__ float hs[512];
  int b = blockIdx.x, e = threadIdx.x;
  const float* hrow = out + (size_t)(2046 * 64 + b) * 512;
  for (int i = threadIdx.x; i < 512; i += 256) hs[i] = hrow[i];
  __syncthreads();
  float acc = be[e];
  const float* wr = We + (size_t)e * 512;
  for (int h = 0; h < 512; ++h) acc += hs[h] * wr[h];
  out[(size_t)OUT_MT + b * 256 + e] = acc;
}

extern "C" void kernel_launch(void* const* d_in, const int* in_sizes, int n_in,
                              void* d_out, int out_size, void* d_ws, size_t ws_size,
                              hipStream_t stream) {
  const float* x   = (const float*)d_in[0];
  const float* h0  = (const float*)d_in[1];
  const float* m0  = (const float*)d_in[2];
  const float* We  = (const float*)d_in[3];
  const float* be  = (const float*)d_in[4];
  const float* Wih = (const float*)d_in[5];
  const float* bih = (const float*)d_in[6];
  float* out = (float*)d_out;
  char* ws = (char*)d_ws;

  _Float16* w2f = (_Float16*)(ws + OFF_W2F);
  _Float16* wxf = (_Float16*)(ws + OFF_WXF);
  float* c2   = (float*)(ws + OFF_C2);
  float* ave  = (float*)(ws + OFF_AVE);
  float* avo  = (float*)(ws + OFF_AVO);
  float* memb = (float*)(ws + OFF_MEMB);
  _Float16* hx = (_Float16*)(ws + OFF_HX);
  unsigned int* flg = (unsigned int*)(ws + OFF_FLG);

  k_memb<<<64, 256, 0, stream>>>(h0, We, be, memb);
  k_prep<<<1795, 256, 0, stream>>>(We, be, Wih, bih, m0, memb, w2f, wxf, c2, ave, avo, flg);
  k_xw<<<1024, 512, 0, stream>>>(x, wxf, out);
  k_main<<<64, 256, 0, stream>>>(w2f, c2, ave, avo, hx, flg, out);
  k_mt<<<64, 256, 0, stream>>>(out, We, be);
}